// Round 7
// baseline (228.852 us; speedup 1.0000x reference)
//
#include <hip/hip_runtime.h>
#include <stdint.h>

typedef int v4i __attribute__((ext_vector_type(4)));

#define AS1(p) ((const __attribute__((address_space(1))) void*)(p))
#define AS3(p) ((__attribute__((address_space(3))) void*)(p))

// ---------------- pack weight: int32 -> int8 ----------------
__global__ __launch_bounds__(256) void pack_w_kernel(
    const int* __restrict__ w, int8_t* __restrict__ w8, int n4)
{
    int t = blockIdx.x * 256 + threadIdx.x;
    if (t >= n4) return;
    int4 v = ((const int4*)w)[t];
    ((int*)w8)[t] = (v.x & 255) | ((v.y & 255) << 8) |
                    ((v.z & 255) << 16) | ((v.w & 255) << 24);
}

// ---------------- fused quant + int8 GEMM ----------------
// BM=64 x BN=256 x BK=64, 256 thr (4 waves 1x4), per-wave out 64x64 (acc[4][4]).
// A: plain float4 loads (compiler-tracked waits -> no rule-18 hazard) -> quant
// VALU -> swizzled ds_write_b128 into 2-buffer int8 As.
// B: 3-deep global_load_lds ring, manual counted vmcnt (never drains prefetch).
#define GK 1024
#define GN 1024
#define NT 16

__device__ __forceinline__ int quant4(float4 v, float isc, float izp) {
    float q0 = fminf(127.f, fmaxf(-128.f, rintf(v.x / isc) + izp));
    float q1 = fminf(127.f, fmaxf(-128.f, rintf(v.y / isc) + izp));
    float q2 = fminf(127.f, fmaxf(-128.f, rintf(v.z / isc) + izp));
    float q3 = fminf(127.f, fmaxf(-128.f, rintf(v.w / isc) + izp));
    return ((int)q0 & 255) | (((int)q1 & 255) << 8) |
           (((int)q2 & 255) << 16) | (((int)q3 & 255) << 24);
}

__global__ __launch_bounds__(256, 2) void fused_kernel(
    const float* __restrict__ X,    // [65536][1024] fp32
    const int8_t* __restrict__ B8,  // [1024][1024] int8
    const int* __restrict__ bias,
    const float* __restrict__ isc_p, const int* __restrict__ izp_p,
    const float* __restrict__ osc_p, const int* __restrict__ ozp_p,
    float* __restrict__ out)
{
    __shared__ int8_t As[2 * 4096];   //  8 KB: 2 x (64 rows x 64 B), swizzled
    __shared__ int8_t Bs[3 * 16384];  // 48 KB: 3 x (256 rows x 64 B), swizzled

    const int tid = threadIdx.x;          // 0..255
    const int w   = tid >> 6, l = tid & 63;
    const int r15 = l & 15,  s4 = l >> 4;

    // XCD-grouped bijective: 4 consecutive logical blocks = one X-panel x 4 bn,
    // all on one XCD -> X-panel read from HBM once, L2 for the other 3.
    const int wg = blockIdx.x;                 // 0..4095
    const int lg = ((wg & 7) << 9) + (wg >> 3);
    const int bm0 = (lg >> 2) << 6;
    const int bn0 = (lg & 3) << 8;

    // scalars needed in-loop: load once, launder, drain before pipeline start
    float isc_r = *isc_p;
    float izp_r = (float)(*izp_p);
    float isc, izp;
    asm volatile("v_mov_b32 %0, %1" : "=v"(isc) : "v"(isc_r));
    asm volatile("v_mov_b32 %0, %1" : "=v"(izp) : "v"(izp_r));
    asm volatile("s_waitcnt vmcnt(0) lgkmcnt(0)" ::: "memory");

    // A source: thread owns row tid>>2, float cols (tid&3)*16 .. +15 of the tile
    const float* a32_src = X + (size_t)(bm0 + (tid >> 2)) * GK + ((tid & 3) << 4);
    // As write: same 16 elems as int8, slot-swizzled (phys = logical ^ ((row>>1)&3))
    const int as_wr = ((tid >> 2) << 6) + ((((tid & 3) ^ ((tid >> 3) & 3))) << 4);

    // B staging: linear LDS dest (lane*16), swizzle pre-applied on global col
    const int8_t* b_src = B8 + (size_t)(bn0 + (tid >> 2)) * GK
                             + ((((tid & 3) ^ ((tid >> 3) & 3))) << 4);

    // fragment reads: same XOR; key reduces to (r15>>1)&3 for all rows used
    const int rc = ((s4 ^ ((r15 >> 1) & 3)) << 4);
    const int a_off0 = ((0 * 16 + r15) << 6) + rc;
    const int a_off1 = ((1 * 16 + r15) << 6) + rc;
    const int a_off2 = ((2 * 16 + r15) << 6) + rc;
    const int a_off3 = ((3 * 16 + r15) << 6) + rc;
    int b_off[4];
#pragma unroll
    for (int j = 0; j < 4; ++j)
        b_off[j] = (((w << 6) + j * 16 + r15) << 6) + rc;

    v4i acc[4][4];
#pragma unroll
    for (int i = 0; i < 4; ++i)
#pragma unroll
        for (int j = 0; j < 4; ++j) acc[i][j] = (v4i){0, 0, 0, 0};

#define SHOT(T, BOFF) do { \
    _Pragma("unroll") \
    for (int c = 0; c < 4; ++c) \
        __builtin_amdgcn_global_load_lds( \
            AS1(b_src + ((size_t)c << 16) + (T) * 64), \
            AS3(&Bs[(BOFF) + (c << 12) + (w << 10)]), 16, 0, 0); \
} while (0)

#define LOADA(T, P0, P1, P2, P3) do { \
    const float4* p_ = (const float4*)(a32_src + (T) * 64); \
    P0 = p_[0]; P1 = p_[1]; P2 = p_[2]; P3 = p_[3]; \
} while (0)

#define QUANT(P0, P1, P2, P3, ABUF) do { \
    int4 wd_ = make_int4(quant4(P0, isc, izp), quant4(P1, isc, izp), \
                         quant4(P2, isc, izp), quant4(P3, isc, izp)); \
    *(int4*)&As[(ABUF) * 4096 + as_wr] = wd_; \
} while (0)

#define COMPUTE(ABUF, BOFF) do { \
    v4i af0 = *(const v4i*)&As[(ABUF) * 4096 + a_off0]; \
    v4i af1 = *(const v4i*)&As[(ABUF) * 4096 + a_off1]; \
    v4i af2 = *(const v4i*)&As[(ABUF) * 4096 + a_off2]; \
    v4i af3 = *(const v4i*)&As[(ABUF) * 4096 + a_off3]; \
    __builtin_amdgcn_s_setprio(1); \
    _Pragma("unroll") \
    for (int j = 0; j < 4; ++j) { \
        v4i bf = *(const v4i*)&Bs[(BOFF) + b_off[j]]; \
        acc[0][j] = __builtin_amdgcn_mfma_i32_16x16x64_i8(af0, bf, acc[0][j], 0, 0, 0); \
        acc[1][j] = __builtin_amdgcn_mfma_i32_16x16x64_i8(af1, bf, acc[1][j], 0, 0, 0); \
        acc[2][j] = __builtin_amdgcn_mfma_i32_16x16x64_i8(af2, bf, acc[2][j], 0, 0, 0); \
        acc[3][j] = __builtin_amdgcn_mfma_i32_16x16x64_i8(af3, bf, acc[3][j], 0, 0, 0); \
    } \
    __builtin_amdgcn_s_setprio(0); \
} while (0)

// Iter T: entry invariant = outstanding vmem == B(T+1)[4] + A32(T+1)[4].
// Issue B(T+2)+A32(T+2); quant A32(T+1) (compiler waits vmcnt(8) for its regs,
// draining B(T+1) in-order while keeping the 8 new ops in flight); guard
// vmcnt(8); compute tile T; lgkm+barrier. Never drains the prefetch.
#define ITER(T, C0, C1, C2, C3, L0, L1, L2, L3) do { \
    SHOT((T) + 2, bb2); \
    LOADA((T) + 2, L0, L1, L2, L3); \
    QUANT(C0, C1, C2, C3, ((T) + 1) & 1); \
    asm volatile("s_waitcnt vmcnt(8)" ::: "memory"); \
    COMPUTE((T) & 1, bb0); \
    asm volatile("s_waitcnt lgkmcnt(0)" ::: "memory"); \
    __builtin_amdgcn_s_barrier(); \
    __builtin_amdgcn_sched_barrier(0); \
    { int tmp_ = bb0; bb0 = bb1; bb1 = bb2; bb2 = tmp_; } \
} while (0)

    float4 x0, x1, x2, x3, y0, y1, y2, y3;
    int bb0 = 0, bb1 = 16384, bb2 = 32768;

    // Prologue: A32(0), B(0), A32(1), B(1); quant(0); leave B(1)+A32(1) in flight.
    LOADA(0, x0, x1, x2, x3);
    SHOT(0, bb0);
    LOADA(1, y0, y1, y2, y3);
    SHOT(1, bb1);
    QUANT(x0, x1, x2, x3, 0);                           // waits A32(0) only
    asm volatile("s_waitcnt vmcnt(8)" ::: "memory");    // B(0) landed
    asm volatile("s_waitcnt lgkmcnt(0)" ::: "memory");
    __builtin_amdgcn_s_barrier();
    __builtin_amdgcn_sched_barrier(0);

#pragma unroll 1
    for (int t = 0; t < NT - 2; t += 2) {
        ITER(t,     y0, y1, y2, y3, x0, x1, x2, x3);  // consume A32(t+1), load A32(t+2)
        ITER(t + 1, x0, x1, x2, x3, y0, y1, y2, y3);
    }

    // T=14: entry outstanding = B(15)+A32(15)=8; no tile 16.
    QUANT(y0, y1, y2, y3, 1);                           // compiler drains to A32(15)
    asm volatile("s_waitcnt vmcnt(0)" ::: "memory");    // B(15) landed
    COMPUTE(0, bb0);                                    // tile 14
    asm volatile("s_waitcnt lgkmcnt(0)" ::: "memory");
    __builtin_amdgcn_s_barrier();
    __builtin_amdgcn_sched_barrier(0);
    COMPUTE(1, bb1);                                    // tile 15

#undef ITER
#undef COMPUTE
#undef QUANT
#undef LOADA
#undef SHOT

    const float osc = *osc_p;
    const int   ozp = *ozp_p;
    int bj[4];
#pragma unroll
    for (int j = 0; j < 4; ++j)
        bj[j] = bias[bn0 + (w << 6) + j * 16 + r15] - ozp;

    // C/D layout (16x16): col = l&15, row = (l>>4)*4 + reg
#pragma unroll
    for (int i = 0; i < 4; ++i) {
        const int mrow = bm0 + i * 16 + s4 * 4;
#pragma unroll
        for (int j = 0; j < 4; ++j) {
            const int n = bn0 + (w << 6) + j * 16 + r15;
            float* op = out + (size_t)mrow * GN + n;
#pragma unroll
            for (int r = 0; r < 4; ++r)
                __builtin_nontemporal_store((float)(acc[i][j][r] + bj[j]) * osc,
                                            op + (size_t)r * GN);
        }
    }
}

extern "C" void kernel_launch(void* const* d_in, const int* in_sizes, int n_in,
                              void* d_out, int out_size, void* d_ws, size_t ws_size,
                              hipStream_t stream)
{
    const float* x         = (const float*)d_in[0];
    const int*   w_int     = (const int*)d_in[1];
    const int*   b_int     = (const int*)d_in[2];
    const float* in_scale  = (const float*)d_in[3];
    const float* out_scale = (const float*)d_in[4];
    const int*   izp       = (const int*)d_in[5];
    const int*   ozp       = (const int*)d_in[6];
    float* out = (float*)d_out;

    int8_t* w8 = (int8_t*)d_ws;   // 1 MB packed weight

    pack_w_kernel<<<1024, 256, 0, stream>>>(w_int, w8, 262144);
    fused_kernel<<<4096, 256, 0, stream>>>(x, w8, b_int,
                                           in_scale, izp, out_scale, ozp, out);
}

// Round 8
// 181.777 us; speedup vs baseline: 1.2590x; 1.2590x over previous
//
#include <hip/hip_runtime.h>
#include <stdint.h>

typedef int v4i __attribute__((ext_vector_type(4)));

#define AS1(p) ((const __attribute__((address_space(1))) void*)(p))
#define AS3(p) ((__attribute__((address_space(3))) void*)(p))

// ---------------- prep: quantize x (blocks 0..16383) + pack W (blocks 16384+) ----
__global__ __launch_bounds__(256) void prep_kernel(
    const float* __restrict__ x, int8_t* __restrict__ xq,
    const int* __restrict__ w, int8_t* __restrict__ w8,
    const float* __restrict__ s_p, const int* __restrict__ izp_p)
{
    const int b = blockIdx.x;
    if (b >= 16384) {                      // pack weight: int32 -> int8
        int t = (b - 16384) * 256 + threadIdx.x;   // 0..262143
        int4 v = ((const int4*)w)[t];
        ((int*)w8)[t] = (v.x & 255) | ((v.y & 255) << 8) |
                        ((v.z & 255) << 16) | ((v.w & 255) << 24);
        return;
    }
    int t = b * 256 + threadIdx.x;         // 16 elements per thread
    float s = *s_p;
    float zp = (float)(*izp_p);
    const float4* xin = (const float4*)x + (size_t)t * 4;
    int words[4];
#pragma unroll
    for (int i = 0; i < 4; ++i) {
        float4 v = xin[i];
        // round-half-even like jnp.round; exact IEEE division like the reference
        float q0 = fminf(127.f, fmaxf(-128.f, rintf(v.x / s) + zp));
        float q1 = fminf(127.f, fmaxf(-128.f, rintf(v.y / s) + zp));
        float q2 = fminf(127.f, fmaxf(-128.f, rintf(v.z / s) + zp));
        float q3 = fminf(127.f, fmaxf(-128.f, rintf(v.w / s) + zp));
        words[i] = ((int)q0 & 255) | (((int)q1 & 255) << 8) |
                   (((int)q2 & 255) << 16) | (((int)q3 & 255) << 24);
    }
    ((int4*)xq)[t] = make_int4(words[0], words[1], words[2], words[3]);
}

// ---------------- int8 GEMM: 256x256 tile, BK=64, 8 waves, 4-phase 8-phase-template ----
// T2 (slot-XOR both-sides) + T3/T4 (per-phase interleave, counted vmcnt once per
// tile, never drain mid-loop) + T5 (setprio around MFMA cluster).
// LDS 64 KB double-buffer -> 2 blocks/CU. NT=16 amortizes the pipeline.
#define GM 65536
#define GN 1024
#define GK 1024
#define NT 16

__global__ __launch_bounds__(512, 2) void gemm_i8_kernel(
    const int8_t* __restrict__ A,   // [GM][GK]
    const int8_t* __restrict__ B,   // [GN][GK]
    const int* __restrict__ bias,
    const float* __restrict__ osc_p, const int* __restrict__ ozp_p,
    float* __restrict__ out)
{
    // tile: 256 rows x 64 B (4 slots of 16 B); phys slot = logical ^ ((row>>1)&3)
    __shared__ int8_t As[2][16384];
    __shared__ int8_t Bs[2][16384];

    const int tid = threadIdx.x;              // 0..511
    const int w   = tid >> 6, l = tid & 63;
    const int wm  = w >> 2,  wn = w & 3;      // 2x4 wave grid, per-wave out 128x64
    const int r15 = l & 15,  s4 = l >> 4;

    // XCD-bijective: wg%8 = XCD, chunk of 128 logical blocks per XCD; 4
    // consecutive logical blocks share one bm-panel (A panel L2-reused x4).
    const int wg = blockIdx.x;                 // 0..1023
    const int lg = ((wg & 7) << 7) + (wg >> 3);
    const int bm0 = (lg >> 2) << 8;
    const int bn0 = (lg & 3) << 8;

    // Staging shot = 8 KB = 128 rows: thread covers row C*128+(tid>>2), 16 B at
    // phys slot tid&3; swizzle pre-applied on the GLOBAL source column.
    const int srow = tid >> 2;
    const int gcol = (((tid & 3) ^ ((tid >> 3) & 3)) << 4);
    const int8_t* aS = A + (size_t)(bm0 + srow) * GK + gcol;
    const int8_t* bS = B + (size_t)(bn0 + srow) * GK + gcol;

#define SHOT_A(T, BUF, C) __builtin_amdgcn_global_load_lds( \
    AS1(aS + (size_t)(C) * 128 * GK + (T) * 64), \
    AS3(&As[BUF][(C) * 8192 + w * 1024]), 16, 0, 0)
#define SHOT_B(T, BUF, C) __builtin_amdgcn_global_load_lds( \
    AS1(bS + (size_t)(C) * 128 * GK + (T) * 64), \
    AS3(&Bs[BUF][(C) * 8192 + w * 1024]), 16, 0, 0)

    // Fragment read bases (same XOR on read; key reduces to (r15>>1)&3).
    const int key = (r15 >> 1) & 3;
    const int a_rd = ((wm * 128 + r15) << 6) + ((s4 ^ key) << 4);  // +1024/frag-row
    const int b_rd = ((wn *  64 + r15) << 6) + ((s4 ^ key) << 4);

    v4i acc[8][4];
#pragma unroll
    for (int i = 0; i < 8; ++i)
#pragma unroll
        for (int j = 0; j < 4; ++j) acc[i][j] = (v4i){0, 0, 0, 0};

    v4i bfr[4];   // B frags cached per K-tile (static indexing)

// Phase P: frag rows 2P,2P+1; STMT = extra work (b-frag loads / staging shot)
// issued before the pre-MFMA barrier. 8 MFMA between the two barriers.
#define PHASE(CUR, P, STMT) do { \
    v4i af0 = *(const v4i*)&As[CUR][a_rd + (P) * 2048]; \
    v4i af1 = *(const v4i*)&As[CUR][a_rd + (P) * 2048 + 1024]; \
    STMT; \
    __builtin_amdgcn_s_barrier(); \
    asm volatile("s_waitcnt lgkmcnt(0)" ::: "memory"); \
    __builtin_amdgcn_s_setprio(1); \
    _Pragma("unroll") \
    for (int j = 0; j < 4; ++j) { \
        acc[(P)*2][j]     = __builtin_amdgcn_mfma_i32_16x16x64_i8(af0, bfr[j], acc[(P)*2][j], 0, 0, 0); \
        acc[(P)*2 + 1][j] = __builtin_amdgcn_mfma_i32_16x16x64_i8(af1, bfr[j], acc[(P)*2 + 1][j], 0, 0, 0); \
    } \
    __builtin_amdgcn_s_setprio(0); \
    __builtin_amdgcn_s_barrier(); \
} while (0)

// Tile T: entry invariant = 4 shots of tile T outstanding (issued during T-1).
// Issue next tile's first shot, THEN vmcnt(1) == "tile T landed" (prefetch
// stays in flight). Remaining 3 shots spread over phases 0-2. Writes go to
// buf nxt, whose last reads (tile T-1) completed before T-1's final barrier.
#define BODY(T, SON) do { \
    const int cur_ = (T) & 1, nxt_ = cur_ ^ 1; \
    if (SON) { \
        SHOT_A((T) + 1, nxt_, 0); \
        asm volatile("s_waitcnt vmcnt(1)" ::: "memory"); \
    } else { \
        asm volatile("s_waitcnt vmcnt(0)" ::: "memory"); \
    } \
    __builtin_amdgcn_s_barrier(); \
    __builtin_amdgcn_sched_barrier(0); \
    PHASE(cur_, 0, { \
        _Pragma("unroll") \
        for (int j = 0; j < 4; ++j) bfr[j] = *(const v4i*)&Bs[cur_][b_rd + j * 1024]; \
        if (SON) SHOT_A((T) + 1, nxt_, 1); }); \
    PHASE(cur_, 1, { if (SON) SHOT_B((T) + 1, nxt_, 0); }); \
    PHASE(cur_, 2, { if (SON) SHOT_B((T) + 1, nxt_, 1); }); \
    PHASE(cur_, 3, ); \
} while (0)

    // Prologue: stage tile 0 fully (4 shots)
    SHOT_A(0, 0, 0); SHOT_A(0, 0, 1);
    SHOT_B(0, 0, 0); SHOT_B(0, 0, 1);

#pragma unroll 1
    for (int t = 0; t < NT - 1; ++t) BODY(t, 1);
    BODY(NT - 1, 0);

#undef BODY
#undef PHASE
#undef SHOT_A
#undef SHOT_B

    const float osc = *osc_p;
    const int   ozp = *ozp_p;
    int bj[4];
#pragma unroll
    for (int j = 0; j < 4; ++j)
        bj[j] = bias[bn0 + wn * 64 + j * 16 + r15] - ozp;

    // C/D layout (16x16): col = l&15, row = (l>>4)*4 + reg
#pragma unroll
    for (int i = 0; i < 8; ++i) {
        const int mrow = bm0 + wm * 128 + i * 16 + s4 * 4;
#pragma unroll
        for (int j = 0; j < 4; ++j) {
            const int n = bn0 + wn * 64 + j * 16 + r15;
            float* op = out + (size_t)mrow * GN + n;
#pragma unroll
            for (int r = 0; r < 4; ++r)
                __builtin_nontemporal_store((float)(acc[i][j][r] + bj[j]) * osc,
                                            op + (size_t)r * GN);
        }
    }
}

extern "C" void kernel_launch(void* const* d_in, const int* in_sizes, int n_in,
                              void* d_out, int out_size, void* d_ws, size_t ws_size,
                              hipStream_t stream)
{
    const float* x         = (const float*)d_in[0];
    const int*   w_int     = (const int*)d_in[1];
    const int*   b_int     = (const int*)d_in[2];
    const float* in_scale  = (const float*)d_in[3];
    const float* out_scale = (const float*)d_in[4];
    const int*   izp       = (const int*)d_in[5];
    const int*   ozp       = (const int*)d_in[6];
    float* out = (float*)d_out;

    int8_t* xq = (int8_t*)d_ws;                            // 64 MB
    int8_t* w8 = (int8_t*)d_ws + (size_t)64 * 1024 * 1024; // 1 MB

    prep_kernel<<<16384 + 1024, 256, 0, stream>>>(x, xq, w_int, w8, in_scale, izp);
    gemm_i8_kernel<<<1024, 512, 0, stream>>>(xq, w8, b_int, out_scale, ozp, out);
}